// Round 6
// baseline (1748.118 us; speedup 1.0000x reference)
//
#include <hip/hip_runtime.h>
#include <math.h>

#define LBL 26
#define MM  14
#define FF  128
#define HH  16
#define WW  8
#define KSZ 5
#define WPB 16              // words per block (fused fallback)
#define LPB (WPB * MM)      // 224
#define NITER 8

// ---------------- kernel 1: fold conv into emission weights ----------------
__global__ void prep_kernel(const float* __restrict__ K,
                            const float* __restrict__ b,
                            const float* __restrict__ W,
                            float* __restrict__ w2,
                            float* __restrict__ cvec) {
    int idx = blockIdx.x * blockDim.x + threadIdx.x;
    int stride = gridDim.x * blockDim.x;
    for (int o = idx; o < LBL * FF; o += stride) {
        int l = o / FF, f = o % FF;
        int qy = f / WW, qx = f % WW;
        double acc = 0.0;
        for (int ky = 0; ky < KSZ; ++ky) {
            int y = qy - ky + 2;
            if (y < 0 || y >= HH) continue;
            for (int kx = 0; kx < KSZ; ++kx) {
                int x = qx - kx + 2;
                if (x < 0 || x >= WW) continue;
                acc += (double)K[ky * KSZ + kx] * (double)W[l * FF + y * WW + x];
            }
        }
        w2[o] = (float)acc;
    }
    for (int l = idx; l < LBL; l += stride) {
        double s = 0.0;
        for (int f = 0; f < FF; ++f) s += (double)W[l * FF + f];
        cvec[l] = (float)(s * (double)b[0]);
    }
}

__device__ __forceinline__ void gload_lds16(const void* g, void* l) {
    __builtin_amdgcn_global_load_lds(
        (const __attribute__((address_space(1))) void*)g,
        (__attribute__((address_space(3))) void*)l, 16, 0, 0);
}

// ---------------- kernel A: emission scores ----------------
// LPT=1 (64 letters/wave), chunk=8 floats, 16 chunks. Quad-buffered per-wave
// LDS X tile via global_load_lds, 6 loads in flight (vmcnt(6) steady state).
// w2 chunk-major in LDS, uniform-address broadcast reads. 46KB LDS, ~60 VGPR.
__global__ __launch_bounds__(256) void scores_kernel(const float* __restrict__ X,
                                                     const float* __restrict__ w2,
                                                     const float* __restrict__ cvec,
                                                     float* __restrict__ sT,
                                                     int NLET) {
    __shared__ float4 wtile[16][LBL][2];   // [chunk][label][sub] : 13312 B
    __shared__ float4 xtile[4][4][128];    // [wave][buf][slot]   : 32768 B

    const int tid  = threadIdx.x;
    const int wv   = tid >> 6;
    const int lane = tid & 63;
    const int wb   = blockIdx.x * 256 + wv * 64;   // wave's first letter

    const float4* X4 = (const float4*)X;
    const float4* W4 = (const float4*)w2;

    // stage w2 chunk-major: W4 idx = l*32 + q, q = c*2 + s
    for (int i = tid; i < 16 * LBL * 2; i += 256) {
        const int l = i >> 5, q = i & 31;
        wtile[q >> 1][l][q & 1] = W4[i];
    }
    __syncthreads();

    const size_t src = (size_t)(wb + lane) * 32;   // float4 units; + c*2 + {0,1}

    float acc[LBL];
#pragma unroll
    for (int l = 0; l < LBL; ++l) acc[l] = cvec[l];

#define ISSUE(c, buf)                                                                 \
    {                                                                                 \
        gload_lds16((const void*)(X4 + src + 2 * (c)),     (void*)&xtile[wv][(buf)][0]);  \
        gload_lds16((const void*)(X4 + src + 2 * (c) + 1), (void*)&xtile[wv][(buf)][64]); \
    }

    ISSUE(0, 0)
    ISSUE(1, 1)
    ISSUE(2, 2)
#pragma unroll
    for (int c = 0; c < 16; ++c) {
        if (c + 3 < 16) {
            ISSUE(c + 3, (c + 3) & 3)
            asm volatile("s_waitcnt vmcnt(6)" ::: "memory");   // chunk c landed; c+1..c+3 in flight
        } else if (c == 13) {
            asm volatile("s_waitcnt vmcnt(4)" ::: "memory");
        } else if (c == 14) {
            asm volatile("s_waitcnt vmcnt(2)" ::: "memory");
        } else {
            asm volatile("s_waitcnt vmcnt(0)" ::: "memory");
        }
        const float4 xa = xtile[wv][c & 3][lane];        // floats 8c..8c+3
        const float4 xb = xtile[wv][c & 3][64 + lane];   // floats 8c+4..8c+7
#pragma unroll
        for (int l = 0; l < LBL; ++l) {
            const float4 w0 = wtile[c][l][0];   // uniform address -> LDS broadcast
            const float4 w1 = wtile[c][l][1];
            float a = acc[l];
            a = fmaf(xa.x, w0.x, a); a = fmaf(xa.y, w0.y, a);
            a = fmaf(xa.z, w0.z, a); a = fmaf(xa.w, w0.w, a);
            a = fmaf(xb.x, w1.x, a); a = fmaf(xb.y, w1.y, a);
            a = fmaf(xb.z, w1.z, a); a = fmaf(xb.w, w1.w, a);
            acc[l] = a;
        }
    }
#undef ISSUE

#pragma unroll
    for (int l = 0; l < LBL; ++l)
        sT[(size_t)l * NLET + wb + lane] = acc[l];   // coalesced 256B per instr
}

// ---------------- kernel B: Viterbi decode (LDS-staged scores, 8 words/block) ----------------
// launch_bounds(256,3): VGPR cap ~170 > ~150 demand -> no spill, 3 waves/SIMD.
__global__ __launch_bounds__(256, 3) void viterbi_kernel(const float* __restrict__ sT,
                                                         const float* __restrict__ Tm,
                                                         int* __restrict__ out,
                                                         int NLET) {
    __shared__ float s_lds[LBL][113];     // 26 x 112 letters (pad 113)
    __shared__ float T_lds[LBL * LBL];
    __shared__ float vb[8][32];

    const int tid  = threadIdx.x;
    const int base = blockIdx.x * 112;    // block's first letter (8 words x 14)

    for (int idx = tid; idx < LBL * 112; idx += 256) {
        const int l = idx / 112, col = idx - l * 112;
        s_lds[l][col] = sT[(size_t)l * NLET + base + col];   // coalesced
    }
    for (int i = tid; i < LBL * LBL; i += 256) T_lds[i] = Tm[i];
    __syncthreads();

    const int wv   = tid >> 6;
    const int lane = tid & 63;
    const int half = lane >> 5;
    const int j    = lane & 31;
    const int jc   = (j < LBL) ? j : 0;

    const int wl   = wv * 2 + half;              // word slot in block
    const int word = blockIdx.x * 8 + wl;

    float tcol[LBL];
#pragma unroll
    for (int i = 0; i < LBL; ++i) tcol[i] = T_lds[i * LBL + jc];

    const float* srow = &s_lds[jc][wl * MM];     // this lane's emission row
    float* vbw = &vb[wl][0];

    float v = (j < LBL) ? srow[0] : -INFINITY;
    if (j < LBL) vbw[j] = v;
    unsigned bp_pack[4] = {0u, 0u, 0u, 0u};

#pragma unroll
    for (int t = 1; t < MM; ++t) {
        float vals[LBL];
        {
            const float4* q = (const float4*)vbw;
            float4 qq;
            qq = q[0]; vals[0]=qq.x+tcol[0]; vals[1]=qq.y+tcol[1]; vals[2]=qq.z+tcol[2]; vals[3]=qq.w+tcol[3];
            qq = q[1]; vals[4]=qq.x+tcol[4]; vals[5]=qq.y+tcol[5]; vals[6]=qq.z+tcol[6]; vals[7]=qq.w+tcol[7];
            qq = q[2]; vals[8]=qq.x+tcol[8]; vals[9]=qq.y+tcol[9]; vals[10]=qq.z+tcol[10]; vals[11]=qq.w+tcol[11];
            qq = q[3]; vals[12]=qq.x+tcol[12]; vals[13]=qq.y+tcol[13]; vals[14]=qq.z+tcol[14]; vals[15]=qq.w+tcol[15];
            qq = q[4]; vals[16]=qq.x+tcol[16]; vals[17]=qq.y+tcol[17]; vals[18]=qq.z+tcol[18]; vals[19]=qq.w+tcol[19];
            qq = q[5]; vals[20]=qq.x+tcol[20]; vals[21]=qq.y+tcol[21]; vals[22]=qq.z+tcol[22]; vals[23]=qq.w+tcol[23];
            qq = q[6]; vals[24]=qq.x+tcol[24]; vals[25]=qq.y+tcol[25];
        }
        // max tree (value identical to sequential max)
        float u0 = fmaxf(vals[0], vals[13]), u1 = fmaxf(vals[1], vals[14]);
        float u2 = fmaxf(vals[2], vals[15]), u3 = fmaxf(vals[3], vals[16]);
        float u4 = fmaxf(vals[4], vals[17]), u5 = fmaxf(vals[5], vals[18]);
        float u6 = fmaxf(vals[6], vals[19]), u7 = fmaxf(vals[7], vals[20]);
        float u8 = fmaxf(vals[8], vals[21]), u9 = fmaxf(vals[9], vals[22]);
        float u10 = fmaxf(vals[10], vals[23]), u11 = fmaxf(vals[11], vals[24]);
        float u12 = fmaxf(vals[12], vals[25]);
        float w0 = fmaxf(u0, u7), w1 = fmaxf(u1, u8), w2_ = fmaxf(u2, u9);
        float w3 = fmaxf(u3, u10), w4 = fmaxf(u4, u11), w5 = fmaxf(u5, u12);
        float x0 = fmaxf(w0, w3), x1 = fmaxf(w1, w4), x2 = fmaxf(w2_, w5);
        float y0 = fmaxf(x0, x1), y1 = fmaxf(x2, u6);
        const float best = fmaxf(y0, y1);
        // first-occurrence argmax via equality mask + ctz
        unsigned m = 0u;
#pragma unroll
        for (int i = LBL - 1; i >= 0; --i) m = m + m + (vals[i] == best ? 1u : 0u);
        const int bi = __builtin_ctz(m);

        v = (j < LBL) ? (best + srow[t]) : -INFINITY;
        if (j < LBL) vbw[j] = v;
        const int k = t - 1;
        bp_pack[k >> 2] |= (unsigned)bi << ((k & 3) * 8);
    }

    // argmax over j of final v (within 32-lane half), first occurrence
    float best = v;
    int bidx = (j < LBL) ? j : 999;
#pragma unroll
    for (int d = 1; d < 32; d <<= 1) {
        const float ov = __shfl_xor(best, d, 64);
        const int oi = __shfl_xor(bidx, d, 64);
        if (ov > best || (ov == best && oi < bidx)) { best = ov; bidx = oi; }
    }

    int cur = bidx;
    if (j == 0) out[word * MM + (MM - 1)] = cur;
#pragma unroll
    for (int k = MM - 2; k >= 0; --k) {
        const unsigned packed = __shfl(bp_pack[k >> 2], (lane & 32) | cur, 64);
        cur = (int)((packed >> ((k & 3) * 8)) & 0xffu);
        if (j == 0) out[word * MM + k] = cur;
    }
}

// ---------------- fallback: round-2 fused kernel (used if d_ws too small) ----------------
__global__ __launch_bounds__(256) void crf_kernel(const float* __restrict__ X,
                                                  const float* __restrict__ T,
                                                  const float* __restrict__ w2,
                                                  const float* __restrict__ cvec,
                                                  int* __restrict__ out) {
    __shared__ float4 tile[LPB * 4];
    __shared__ float  s_lds[WPB * MM * LBL];
    __shared__ float  v_lds[WPB * 32];

    const int tid = threadIdx.x;
    const int blk = blockIdx.x;
    const float4* X4 = (const float4*)X + (size_t)blk * LPB * (FF / 4);
    const float4* W4 = (const float4*)w2;

    float acc[LBL];
    if (tid < LPB) {
#pragma unroll
        for (int l = 0; l < LBL; ++l) acc[l] = cvec[l];
    }
    const int c0 = tid, c1 = tid + 256, c2 = tid + 512, c3 = tid + 768;
    float4 st0, st1, st2, st3;
    st0 = X4[(c0 >> 2) * 32 + (c0 & 3)];
    st1 = X4[(c1 >> 2) * 32 + (c1 & 3)];
    st2 = X4[(c2 >> 2) * 32 + (c2 & 3)];
    if (tid < 128) st3 = X4[(c3 >> 2) * 32 + (c3 & 3)];

    for (int iter = 0; iter < NITER; ++iter) {
        tile[(c0 >> 2) * 4 + ((c0 & 3) ^ ((c0 >> 2) & 3))] = st0;
        tile[(c1 >> 2) * 4 + ((c1 & 3) ^ ((c1 >> 2) & 3))] = st1;
        tile[(c2 >> 2) * 4 + ((c2 & 3) ^ ((c2 >> 2) & 3))] = st2;
        if (tid < 128) tile[(c3 >> 2) * 4 + ((c3 & 3) ^ ((c3 >> 2) & 3))] = st3;
        __syncthreads();
        if (iter + 1 < NITER) {
            const int ofs = (iter + 1) * 4;
            st0 = X4[(c0 >> 2) * 32 + ofs + (c0 & 3)];
            st1 = X4[(c1 >> 2) * 32 + ofs + (c1 & 3)];
            st2 = X4[(c2 >> 2) * 32 + ofs + (c2 & 3)];
            if (tid < 128) st3 = X4[(c3 >> 2) * 32 + ofs + (c3 & 3)];
        }
        if (tid < LPB) {
            const float4 xv0 = tile[tid * 4 + (0 ^ (tid & 3))];
            const float4 xv1 = tile[tid * 4 + (1 ^ (tid & 3))];
            const float4 xv2 = tile[tid * 4 + (2 ^ (tid & 3))];
            const float4 xv3 = tile[tid * 4 + (3 ^ (tid & 3))];
#pragma unroll
            for (int l = 0; l < LBL; ++l) {
                const float4 w0 = W4[l * 32 + iter * 4 + 0];
                const float4 w1 = W4[l * 32 + iter * 4 + 1];
                const float4 w2v = W4[l * 32 + iter * 4 + 2];
                const float4 w3 = W4[l * 32 + iter * 4 + 3];
                float a = acc[l];
                a = fmaf(xv0.x, w0.x, a); a = fmaf(xv0.y, w0.y, a);
                a = fmaf(xv0.z, w0.z, a); a = fmaf(xv0.w, w0.w, a);
                a = fmaf(xv1.x, w1.x, a); a = fmaf(xv1.y, w1.y, a);
                a = fmaf(xv1.z, w1.z, a); a = fmaf(xv1.w, w1.w, a);
                a = fmaf(xv2.x, w2v.x, a); a = fmaf(xv2.y, w2v.y, a);
                a = fmaf(xv2.z, w2v.z, a); a = fmaf(xv2.w, w2v.w, a);
                a = fmaf(xv3.x, w3.x, a); a = fmaf(xv3.y, w3.y, a);
                a = fmaf(xv3.z, w3.z, a); a = fmaf(xv3.w, w3.w, a);
                acc[l] = a;
            }
        }
        __syncthreads();
    }
    if (tid < LPB) {
#pragma unroll
        for (int l = 0; l < LBL; ++l) s_lds[tid * LBL + l] = acc[l];
    }
    __syncthreads();

    const int lane = tid & 63;
    const int wvid = tid >> 6;
    const int half = lane >> 5;
    const int j = lane & 31;
    const int jc = (j < LBL) ? j : 0;

    float tcol[LBL];
#pragma unroll
    for (int i = 0; i < LBL; ++i) tcol[i] = T[i * LBL + jc];

    for (int pass = 0; pass < 2; ++pass) {
        const int wi = pass * 8 + wvid * 2 + half;
        const int word = blk * WPB + wi;
        const float* sw = s_lds + wi * MM * LBL;
        float* vbp = v_lds + wi * 32;

        float v = (j < LBL) ? sw[j] : -INFINITY;
        if (j < LBL) vbp[j] = v;
        unsigned bp_pack[4] = {0u, 0u, 0u, 0u};

#pragma unroll
        for (int t = 1; t < MM; ++t) {
            float best = -INFINITY;
            int bi = 0;
#define VCHK(vexpr, idx) { const float val = (vexpr) + tcol[idx]; \
                           if (val > best) { best = val; bi = idx; } }
            {
                float4 vv;
                vv = *(const float4*)(vbp + 0);
                VCHK(vv.x, 0) VCHK(vv.y, 1) VCHK(vv.z, 2) VCHK(vv.w, 3)
                vv = *(const float4*)(vbp + 4);
                VCHK(vv.x, 4) VCHK(vv.y, 5) VCHK(vv.z, 6) VCHK(vv.w, 7)
                vv = *(const float4*)(vbp + 8);
                VCHK(vv.x, 8) VCHK(vv.y, 9) VCHK(vv.z, 10) VCHK(vv.w, 11)
                vv = *(const float4*)(vbp + 12);
                VCHK(vv.x, 12) VCHK(vv.y, 13) VCHK(vv.z, 14) VCHK(vv.w, 15)
                vv = *(const float4*)(vbp + 16);
                VCHK(vv.x, 16) VCHK(vv.y, 17) VCHK(vv.z, 18) VCHK(vv.w, 19)
                vv = *(const float4*)(vbp + 20);
                VCHK(vv.x, 20) VCHK(vv.y, 21) VCHK(vv.z, 22) VCHK(vv.w, 23)
                vv = *(const float4*)(vbp + 24);
                VCHK(vv.x, 24) VCHK(vv.y, 25)
            }
#undef VCHK
            v = (j < LBL) ? (best + sw[t * LBL + j]) : -INFINITY;
            if (j < LBL) vbp[j] = v;
            const int k = t - 1;
            bp_pack[k >> 2] |= (unsigned)bi << ((k & 3) * 8);
        }

        float best = v;
        int bidx = (j < LBL) ? j : 999;
#pragma unroll
        for (int d = 1; d < 32; d <<= 1) {
            const float ov = __shfl_xor(best, d, 64);
            const int oi = __shfl_xor(bidx, d, 64);
            if (ov > best || (ov == best && oi < bidx)) { best = ov; bidx = oi; }
        }
        int cur = bidx;
        if (j == 0) out[word * MM + (MM - 1)] = cur;
#pragma unroll
        for (int k = MM - 2; k >= 0; --k) {
            const unsigned packed = __shfl(bp_pack[k >> 2], (lane & 32) | cur, 64);
            cur = (int)((packed >> ((k & 3) * 8)) & 0xffu);
            if (j == 0) out[word * MM + k] = cur;
        }
        __syncthreads();
    }
}

extern "C" void kernel_launch(void* const* d_in, const int* in_sizes, int n_in,
                              void* d_out, int out_size, void* d_ws, size_t ws_size,
                              hipStream_t stream) {
    const float* X = (const float*)d_in[0];
    const float* K = (const float*)d_in[1];
    const float* b = (const float*)d_in[2];
    const float* W = (const float*)d_in[3];
    const float* T = (const float*)d_in[4];
    int* out = (int*)d_out;

    const int nw = in_sizes[0] / (MM * FF);     // 32768 words
    const int NLET = nw * MM;                   // 458752 letters

    const size_t sT_bytes = (size_t)LBL * NLET * sizeof(float);   // ~47.7 MB
    const size_t w_bytes  = (size_t)(LBL * FF + LBL) * sizeof(float);

    if (ws_size >= sT_bytes + w_bytes && (NLET % 256) == 0 && (nw % 8) == 0) {
        float* sT   = (float*)d_ws;
        float* w2   = (float*)((char*)d_ws + sT_bytes);
        float* cvec = w2 + LBL * FF;
        prep_kernel<<<(LBL * FF + 255) / 256, 256, 0, stream>>>(K, b, W, w2, cvec);
        scores_kernel<<<NLET / 256, 256, 0, stream>>>(X, w2, cvec, sT, NLET);
        viterbi_kernel<<<nw / 8, 256, 0, stream>>>(sT, T, out, NLET);
    } else {
        float* w2   = (float*)d_ws;
        float* cvec = w2 + LBL * FF;
        prep_kernel<<<(LBL * FF + 255) / 256, 256, 0, stream>>>(K, b, W, w2, cvec);
        crf_kernel<<<nw / WPB, 256, 0, stream>>>(X, T, w2, cvec, out);
    }
}

// Round 7
// 332.650 us; speedup vs baseline: 5.2551x; 5.2551x over previous
//
#include <hip/hip_runtime.h>
#include <math.h>

#define LBL 26
#define MM  14
#define FF  128
#define HH  16
#define WW  8
#define KSZ 5
#define WPB 16              // words per block (fused fallback)
#define LPB (WPB * MM)      // 224
#define NITER 8

// ---------------- kernel 1: fold conv into emission weights ----------------
__global__ void prep_kernel(const float* __restrict__ K,
                            const float* __restrict__ b,
                            const float* __restrict__ W,
                            float* __restrict__ w2,
                            float* __restrict__ cvec) {
    int idx = blockIdx.x * blockDim.x + threadIdx.x;
    int stride = gridDim.x * blockDim.x;
    for (int o = idx; o < LBL * FF; o += stride) {
        int l = o / FF, f = o % FF;
        int qy = f / WW, qx = f % WW;
        double acc = 0.0;
        for (int ky = 0; ky < KSZ; ++ky) {
            int y = qy - ky + 2;
            if (y < 0 || y >= HH) continue;
            for (int kx = 0; kx < KSZ; ++kx) {
                int x = qx - kx + 2;
                if (x < 0 || x >= WW) continue;
                acc += (double)K[ky * KSZ + kx] * (double)W[l * FF + y * WW + x];
            }
        }
        w2[o] = (float)acc;
    }
    for (int l = idx; l < LBL; l += stride) {
        double s = 0.0;
        for (int f = 0; f < FF; ++f) s += (double)W[l * FF + f];
        cvec[l] = (float)(s * (double)b[0]);
    }
}

__device__ __forceinline__ void gload_lds16(const void* g, void* l) {
    __builtin_amdgcn_global_load_lds(
        (const __attribute__((address_space(1))) void*)g,
        (__attribute__((address_space(3))) void*)l, 16, 0, 0);
}

// ---------------- kernel A: emission scores ----------------
// LPT=2 (128 letters/wave), chunk=8 floats, 16 chunks, 2-buf, vmcnt(4).
// w2 via wave-uniform LDS broadcast (wtile). X tile slots = part*128+letter
// so all ds_read_b128 are lane-consecutive (conflict-free). NO unroll on the
// chunk loop (r6 lesson: unrolled gload addresses -> VGPR explosion).
__global__ __launch_bounds__(256) void scores_kernel(const float* __restrict__ X,
                                                     const float* __restrict__ w2,
                                                     const float* __restrict__ cvec,
                                                     float* __restrict__ sT,
                                                     int NLET) {
    __shared__ float4 wtile[16][LBL][2];   // [chunk][label][part] : 13312 B
    __shared__ float4 xtile[4][2][256];    // [wave][buf][slot], slot=part*128+letter : 32768 B

    const int tid  = threadIdx.x;
    const int wv   = tid >> 6;
    const int lane = tid & 63;
    const int wb   = blockIdx.x * 512 + wv * 128;   // wave's first letter

    const float4* X4 = (const float4*)X;
    const float4* W4 = (const float4*)w2;

    // stage w2 chunk-major: W4 idx i = l*32 + c*2 + p
    for (int i = tid; i < 16 * LBL * 2; i += 256) {
        const int l = i >> 5, q = i & 31;
        wtile[q >> 1][l][q & 1] = W4[i];
    }
    __syncthreads();

    // gload g: letters (g&1)*64..+63, part g>>1 -> slots (g>>1)*128 + (g&1)*64 + lane
    const size_t s0 = (size_t)(wb + lane) * 32;        // float4 units (letter A group)
    const size_t s1 = (size_t)(wb + 64 + lane) * 32;   // letter B group

    float acc[2 * LBL];
#pragma unroll
    for (int l = 0; l < LBL; ++l) { acc[l] = cvec[l]; acc[LBL + l] = cvec[l]; }

#define ISSUE(c, buf)                                                                \
    {                                                                                \
        float4* dst = &xtile[wv][(buf)][0];                                          \
        gload_lds16((const void*)(X4 + s0 + 2 * (c)),     (void*)(dst + 0));         \
        gload_lds16((const void*)(X4 + s1 + 2 * (c)),     (void*)(dst + 64));        \
        gload_lds16((const void*)(X4 + s0 + 2 * (c) + 1), (void*)(dst + 128));       \
        gload_lds16((const void*)(X4 + s1 + 2 * (c) + 1), (void*)(dst + 192));       \
    }

    ISSUE(0, 0)
    for (int c = 0; c < 16; ++c) {     // deliberately NOT unrolled
        if (c < 15) {
            ISSUE(c + 1, (c + 1) & 1)
            asm volatile("s_waitcnt vmcnt(4)" ::: "memory");   // chunk c landed, c+1 in flight
        } else {
            asm volatile("s_waitcnt vmcnt(0)" ::: "memory");
        }
        const float4* tb = &xtile[wv][c & 1][0];
        const float4 xa0 = tb[lane];          // letter lane,    feats 8c..8c+3
        const float4 xa1 = tb[128 + lane];    // letter lane,    feats 8c+4..8c+7
        const float4 xb0 = tb[64 + lane];     // letter 64+lane, feats 8c..8c+3
        const float4 xb1 = tb[192 + lane];    // letter 64+lane, feats 8c+4..8c+7
#pragma unroll
        for (int l = 0; l < LBL; ++l) {
            const float4 w0 = wtile[c][l][0];   // wave-uniform -> LDS broadcast
            const float4 w1 = wtile[c][l][1];
            float a = acc[l];
            a = fmaf(xa0.x, w0.x, a); a = fmaf(xa0.y, w0.y, a);
            a = fmaf(xa0.z, w0.z, a); a = fmaf(xa0.w, w0.w, a);
            a = fmaf(xa1.x, w1.x, a); a = fmaf(xa1.y, w1.y, a);
            a = fmaf(xa1.z, w1.z, a); a = fmaf(xa1.w, w1.w, a);
            acc[l] = a;
            float bq = acc[LBL + l];
            bq = fmaf(xb0.x, w0.x, bq); bq = fmaf(xb0.y, w0.y, bq);
            bq = fmaf(xb0.z, w0.z, bq); bq = fmaf(xb0.w, w0.w, bq);
            bq = fmaf(xb1.x, w1.x, bq); bq = fmaf(xb1.y, w1.y, bq);
            bq = fmaf(xb1.z, w1.z, bq); bq = fmaf(xb1.w, w1.w, bq);
            acc[LBL + l] = bq;
        }
    }
#undef ISSUE

#pragma unroll
    for (int l = 0; l < LBL; ++l) {
        sT[(size_t)l * NLET + wb + lane]      = acc[l];         // coalesced
        sT[(size_t)l * NLET + wb + 64 + lane] = acc[LBL + l];
    }
}

// ---------------- kernel B: Viterbi decode (register-dieted, natural VGPR) ----------------
// ~50 VGPR target: no s[] prefetch, no vals[] array (two-pass: fmax chains,
// then recomputed equality mask). t-loop unrolled so bp_pack stays in regs.
__global__ __launch_bounds__(256) void viterbi_kernel(const float* __restrict__ sT,
                                                      const float* __restrict__ Tm,
                                                      int* __restrict__ out,
                                                      int NLET) {
    __shared__ float s_lds[LBL][113];     // 26 x 112 letters (pad 113)
    __shared__ float T_lds[LBL * LBL];
    __shared__ float vb[8][32];

    const int tid  = threadIdx.x;
    const int base = blockIdx.x * 112;    // block's first letter (8 words x 14)

    for (int idx = tid; idx < LBL * 112; idx += 256) {
        const int l = idx / 112, col = idx - l * 112;
        s_lds[l][col] = sT[(size_t)l * NLET + base + col];   // coalesced
    }
    for (int i = tid; i < LBL * LBL; i += 256) T_lds[i] = Tm[i];
    __syncthreads();

    const int wv   = tid >> 6;
    const int lane = tid & 63;
    const int half = lane >> 5;
    const int j    = lane & 31;
    const int jc   = (j < LBL) ? j : 0;

    const int wl   = wv * 2 + half;              // word slot in block
    const int word = blockIdx.x * 8 + wl;

    float tcol[LBL];
#pragma unroll
    for (int i = 0; i < LBL; ++i) tcol[i] = T_lds[i * LBL + jc];

    const float* srow = &s_lds[jc][wl * MM];
    float* vbw = &vb[wl][0];

    float v = (j < LBL) ? srow[0] : -INFINITY;
    if (j < LBL) vbw[j] = v;
    unsigned bp_pack[4] = {0u, 0u, 0u, 0u};

#pragma unroll
    for (int t = 1; t < MM; ++t) {
        const float4* q4 = (const float4*)vbw;   // 2 uniform addrs/wave -> broadcast
        // pass 1: best via 4 parallel fmax chains (value == sequential max)
        float4 qq = q4[0];
        float b0 = qq.x + tcol[0], b1 = qq.y + tcol[1];
        float b2 = qq.z + tcol[2], b3 = qq.w + tcol[3];
        qq = q4[1];
        b0 = fmaxf(b0, qq.x + tcol[4]);  b1 = fmaxf(b1, qq.y + tcol[5]);
        b2 = fmaxf(b2, qq.z + tcol[6]);  b3 = fmaxf(b3, qq.w + tcol[7]);
        qq = q4[2];
        b0 = fmaxf(b0, qq.x + tcol[8]);  b1 = fmaxf(b1, qq.y + tcol[9]);
        b2 = fmaxf(b2, qq.z + tcol[10]); b3 = fmaxf(b3, qq.w + tcol[11]);
        qq = q4[3];
        b0 = fmaxf(b0, qq.x + tcol[12]); b1 = fmaxf(b1, qq.y + tcol[13]);
        b2 = fmaxf(b2, qq.z + tcol[14]); b3 = fmaxf(b3, qq.w + tcol[15]);
        qq = q4[4];
        b0 = fmaxf(b0, qq.x + tcol[16]); b1 = fmaxf(b1, qq.y + tcol[17]);
        b2 = fmaxf(b2, qq.z + tcol[18]); b3 = fmaxf(b3, qq.w + tcol[19]);
        qq = q4[5];
        b0 = fmaxf(b0, qq.x + tcol[20]); b1 = fmaxf(b1, qq.y + tcol[21]);
        b2 = fmaxf(b2, qq.z + tcol[22]); b3 = fmaxf(b3, qq.w + tcol[23]);
        qq = q4[6];
        b0 = fmaxf(b0, qq.x + tcol[24]); b1 = fmaxf(b1, qq.y + tcol[25]);
        const float best = fmaxf(fmaxf(b0, b1), fmaxf(b2, b3));

        // pass 2: first-occurrence mask, i = 25 .. 0 (recomputed adds are bit-identical)
        unsigned m = 0u;
        qq = q4[6];
        m = m + m + (qq.y + tcol[25] == best ? 1u : 0u);
        m = m + m + (qq.x + tcol[24] == best ? 1u : 0u);
        qq = q4[5];
        m = m + m + (qq.w + tcol[23] == best ? 1u : 0u);
        m = m + m + (qq.z + tcol[22] == best ? 1u : 0u);
        m = m + m + (qq.y + tcol[21] == best ? 1u : 0u);
        m = m + m + (qq.x + tcol[20] == best ? 1u : 0u);
        qq = q4[4];
        m = m + m + (qq.w + tcol[19] == best ? 1u : 0u);
        m = m + m + (qq.z + tcol[18] == best ? 1u : 0u);
        m = m + m + (qq.y + tcol[17] == best ? 1u : 0u);
        m = m + m + (qq.x + tcol[16] == best ? 1u : 0u);
        qq = q4[3];
        m = m + m + (qq.w + tcol[15] == best ? 1u : 0u);
        m = m + m + (qq.z + tcol[14] == best ? 1u : 0u);
        m = m + m + (qq.y + tcol[13] == best ? 1u : 0u);
        m = m + m + (qq.x + tcol[12] == best ? 1u : 0u);
        qq = q4[2];
        m = m + m + (qq.w + tcol[11] == best ? 1u : 0u);
        m = m + m + (qq.z + tcol[10] == best ? 1u : 0u);
        m = m + m + (qq.y + tcol[9]  == best ? 1u : 0u);
        m = m + m + (qq.x + tcol[8]  == best ? 1u : 0u);
        qq = q4[1];
        m = m + m + (qq.w + tcol[7]  == best ? 1u : 0u);
        m = m + m + (qq.z + tcol[6]  == best ? 1u : 0u);
        m = m + m + (qq.y + tcol[5]  == best ? 1u : 0u);
        m = m + m + (qq.x + tcol[4]  == best ? 1u : 0u);
        qq = q4[0];
        m = m + m + (qq.w + tcol[3]  == best ? 1u : 0u);
        m = m + m + (qq.z + tcol[2]  == best ? 1u : 0u);
        m = m + m + (qq.y + tcol[1]  == best ? 1u : 0u);
        m = m + m + (qq.x + tcol[0]  == best ? 1u : 0u);
        const int bi = __builtin_ctz(m);

        v = (j < LBL) ? (best + srow[t]) : -INFINITY;
        if (j < LBL) vbw[j] = v;
        const int k = t - 1;
        bp_pack[k >> 2] |= (unsigned)bi << ((k & 3) * 8);
    }

    // argmax over j of final v (within 32-lane half), first occurrence
    float best = v;
    int bidx = (j < LBL) ? j : 999;
#pragma unroll
    for (int d = 1; d < 32; d <<= 1) {
        const float ov = __shfl_xor(best, d, 64);
        const int oi = __shfl_xor(bidx, d, 64);
        if (ov > best || (ov == best && oi < bidx)) { best = ov; bidx = oi; }
    }

    int cur = bidx;
    if (j == 0) out[word * MM + (MM - 1)] = cur;
#pragma unroll
    for (int k = MM - 2; k >= 0; --k) {
        const unsigned packed = __shfl(bp_pack[k >> 2], (lane & 32) | cur, 64);
        cur = (int)((packed >> ((k & 3) * 8)) & 0xffu);
        if (j == 0) out[word * MM + k] = cur;
    }
}

// ---------------- fallback: round-2 fused kernel (used if d_ws too small) ----------------
__global__ __launch_bounds__(256) void crf_kernel(const float* __restrict__ X,
                                                  const float* __restrict__ T,
                                                  const float* __restrict__ w2,
                                                  const float* __restrict__ cvec,
                                                  int* __restrict__ out) {
    __shared__ float4 tile[LPB * 4];
    __shared__ float  s_lds[WPB * MM * LBL];
    __shared__ float  v_lds[WPB * 32];

    const int tid = threadIdx.x;
    const int blk = blockIdx.x;
    const float4* X4 = (const float4*)X + (size_t)blk * LPB * (FF / 4);
    const float4* W4 = (const float4*)w2;

    float acc[LBL];
    if (tid < LPB) {
#pragma unroll
        for (int l = 0; l < LBL; ++l) acc[l] = cvec[l];
    }
    const int c0 = tid, c1 = tid + 256, c2 = tid + 512, c3 = tid + 768;
    float4 st0, st1, st2, st3;
    st0 = X4[(c0 >> 2) * 32 + (c0 & 3)];
    st1 = X4[(c1 >> 2) * 32 + (c1 & 3)];
    st2 = X4[(c2 >> 2) * 32 + (c2 & 3)];
    if (tid < 128) st3 = X4[(c3 >> 2) * 32 + (c3 & 3)];

    for (int iter = 0; iter < NITER; ++iter) {
        tile[(c0 >> 2) * 4 + ((c0 & 3) ^ ((c0 >> 2) & 3))] = st0;
        tile[(c1 >> 2) * 4 + ((c1 & 3) ^ ((c1 >> 2) & 3))] = st1;
        tile[(c2 >> 2) * 4 + ((c2 & 3) ^ ((c2 >> 2) & 3))] = st2;
        if (tid < 128) tile[(c3 >> 2) * 4 + ((c3 & 3) ^ ((c3 >> 2) & 3))] = st3;
        __syncthreads();
        if (iter + 1 < NITER) {
            const int ofs = (iter + 1) * 4;
            st0 = X4[(c0 >> 2) * 32 + ofs + (c0 & 3)];
            st1 = X4[(c1 >> 2) * 32 + ofs + (c1 & 3)];
            st2 = X4[(c2 >> 2) * 32 + ofs + (c2 & 3)];
            if (tid < 128) st3 = X4[(c3 >> 2) * 32 + ofs + (c3 & 3)];
        }
        if (tid < LPB) {
            const float4 xv0 = tile[tid * 4 + (0 ^ (tid & 3))];
            const float4 xv1 = tile[tid * 4 + (1 ^ (tid & 3))];
            const float4 xv2 = tile[tid * 4 + (2 ^ (tid & 3))];
            const float4 xv3 = tile[tid * 4 + (3 ^ (tid & 3))];
#pragma unroll
            for (int l = 0; l < LBL; ++l) {
                const float4 w0 = W4[l * 32 + iter * 4 + 0];
                const float4 w1 = W4[l * 32 + iter * 4 + 1];
                const float4 w2v = W4[l * 32 + iter * 4 + 2];
                const float4 w3 = W4[l * 32 + iter * 4 + 3];
                float a = acc[l];
                a = fmaf(xv0.x, w0.x, a); a = fmaf(xv0.y, w0.y, a);
                a = fmaf(xv0.z, w0.z, a); a = fmaf(xv0.w, w0.w, a);
                a = fmaf(xv1.x, w1.x, a); a = fmaf(xv1.y, w1.y, a);
                a = fmaf(xv1.z, w1.z, a); a = fmaf(xv1.w, w1.w, a);
                a = fmaf(xv2.x, w2v.x, a); a = fmaf(xv2.y, w2v.y, a);
                a = fmaf(xv2.z, w2v.z, a); a = fmaf(xv2.w, w2v.w, a);
                a = fmaf(xv3.x, w3.x, a); a = fmaf(xv3.y, w3.y, a);
                a = fmaf(xv3.z, w3.z, a); a = fmaf(xv3.w, w3.w, a);
                acc[l] = a;
            }
        }
        __syncthreads();
    }
    if (tid < LPB) {
#pragma unroll
        for (int l = 0; l < LBL; ++l) s_lds[tid * LBL + l] = acc[l];
    }
    __syncthreads();

    const int lane = tid & 63;
    const int wvid = tid >> 6;
    const int half = lane >> 5;
    const int j = lane & 31;
    const int jc = (j < LBL) ? j : 0;

    float tcol[LBL];
#pragma unroll
    for (int i = 0; i < LBL; ++i) tcol[i] = T[i * LBL + jc];

    for (int pass = 0; pass < 2; ++pass) {
        const int wi = pass * 8 + wvid * 2 + half;
        const int word = blk * WPB + wi;
        const float* sw = s_lds + wi * MM * LBL;
        float* vbp = v_lds + wi * 32;

        float v = (j < LBL) ? sw[j] : -INFINITY;
        if (j < LBL) vbp[j] = v;
        unsigned bp_pack[4] = {0u, 0u, 0u, 0u};

#pragma unroll
        for (int t = 1; t < MM; ++t) {
            float best = -INFINITY;
            int bi = 0;
#define VCHK(vexpr, idx) { const float val = (vexpr) + tcol[idx]; \
                           if (val > best) { best = val; bi = idx; } }
            {
                float4 vv;
                vv = *(const float4*)(vbp + 0);
                VCHK(vv.x, 0) VCHK(vv.y, 1) VCHK(vv.z, 2) VCHK(vv.w, 3)
                vv = *(const float4*)(vbp + 4);
                VCHK(vv.x, 4) VCHK(vv.y, 5) VCHK(vv.z, 6) VCHK(vv.w, 7)
                vv = *(const float4*)(vbp + 8);
                VCHK(vv.x, 8) VCHK(vv.y, 9) VCHK(vv.z, 10) VCHK(vv.w, 11)
                vv = *(const float4*)(vbp + 12);
                VCHK(vv.x, 12) VCHK(vv.y, 13) VCHK(vv.z, 14) VCHK(vv.w, 15)
                vv = *(const float4*)(vbp + 16);
                VCHK(vv.x, 16) VCHK(vv.y, 17) VCHK(vv.z, 18) VCHK(vv.w, 19)
                vv = *(const float4*)(vbp + 20);
                VCHK(vv.x, 20) VCHK(vv.y, 21) VCHK(vv.z, 22) VCHK(vv.w, 23)
                vv = *(const float4*)(vbp + 24);
                VCHK(vv.x, 24) VCHK(vv.y, 25)
            }
#undef VCHK
            v = (j < LBL) ? (best + sw[t * LBL + j]) : -INFINITY;
            if (j < LBL) vbp[j] = v;
            const int k = t - 1;
            bp_pack[k >> 2] |= (unsigned)bi << ((k & 3) * 8);
        }

        float best = v;
        int bidx = (j < LBL) ? j : 999;
#pragma unroll
        for (int d = 1; d < 32; d <<= 1) {
            const float ov = __shfl_xor(best, d, 64);
            const int oi = __shfl_xor(bidx, d, 64);
            if (ov > best || (ov == best && oi < bidx)) { best = ov; bidx = oi; }
        }
        int cur = bidx;
        if (j == 0) out[word * MM + (MM - 1)] = cur;
#pragma unroll
        for (int k = MM - 2; k >= 0; --k) {
            const unsigned packed = __shfl(bp_pack[k >> 2], (lane & 32) | cur, 64);
            cur = (int)((packed >> ((k & 3) * 8)) & 0xffu);
            if (j == 0) out[word * MM + k] = cur;
        }
        __syncthreads();
    }
}

extern "C" void kernel_launch(void* const* d_in, const int* in_sizes, int n_in,
                              void* d_out, int out_size, void* d_ws, size_t ws_size,
                              hipStream_t stream) {
    const float* X = (const float*)d_in[0];
    const float* K = (const float*)d_in[1];
    const float* b = (const float*)d_in[2];
    const float* W = (const float*)d_in[3];
    const float* T = (const float*)d_in[4];
    int* out = (int*)d_out;

    const int nw = in_sizes[0] / (MM * FF);     // 32768 words
    const int NLET = nw * MM;                   // 458752 letters

    const size_t sT_bytes = (size_t)LBL * NLET * sizeof(float);   // ~47.7 MB
    const size_t w_bytes  = (size_t)(LBL * FF + LBL) * sizeof(float);

    if (ws_size >= sT_bytes + w_bytes && (NLET % 512) == 0 && (nw % 8) == 0) {
        float* sT   = (float*)d_ws;
        float* w2   = (float*)((char*)d_ws + sT_bytes);
        float* cvec = w2 + LBL * FF;
        prep_kernel<<<(LBL * FF + 255) / 256, 256, 0, stream>>>(K, b, W, w2, cvec);
        scores_kernel<<<NLET / 512, 256, 0, stream>>>(X, w2, cvec, sT, NLET);
        viterbi_kernel<<<nw / 8, 256, 0, stream>>>(sT, T, out, NLET);
    } else {
        float* w2   = (float*)d_ws;
        float* cvec = w2 + LBL * FF;
        prep_kernel<<<(LBL * FF + 255) / 256, 256, 0, stream>>>(K, b, W, w2, cvec);
        crf_kernel<<<nw / WPB, 256, 0, stream>>>(X, T, w2, cvec, out);
    }
}

// Round 8
// 268.432 us; speedup vs baseline: 6.5123x; 1.2392x over previous
//
#include <hip/hip_runtime.h>
#include <math.h>

#define LBL 26
#define MM  14
#define FF  128
#define HH  16
#define WW  8
#define KSZ 5
#define WPB 16              // words per block (fused fallback)
#define LPB (WPB * MM)      // 224
#define NITER 8

// ---------------- kernel 1: fold conv into emission weights ----------------
__global__ void prep_kernel(const float* __restrict__ K,
                            const float* __restrict__ b,
                            const float* __restrict__ W,
                            float* __restrict__ w2,
                            float* __restrict__ cvec) {
    int idx = blockIdx.x * blockDim.x + threadIdx.x;
    int stride = gridDim.x * blockDim.x;
    for (int o = idx; o < LBL * FF; o += stride) {
        int l = o / FF, f = o % FF;
        int qy = f / WW, qx = f % WW;
        double acc = 0.0;
        for (int ky = 0; ky < KSZ; ++ky) {
            int y = qy - ky + 2;
            if (y < 0 || y >= HH) continue;
            for (int kx = 0; kx < KSZ; ++kx) {
                int x = qx - kx + 2;
                if (x < 0 || x >= WW) continue;
                acc += (double)K[ky * KSZ + kx] * (double)W[l * FF + y * WW + x];
            }
        }
        w2[o] = (float)acc;
    }
    for (int l = idx; l < LBL; l += stride) {
        double s = 0.0;
        for (int f = 0; f < FF; ++f) s += (double)W[l * FF + f];
        cvec[l] = (float)(s * (double)b[0]);
    }
}

// ---------------- kernel A: emission scores (register-staged) ----------------
// Thread = one letter. X row read as 4 back-to-back dwordx4 per 64B line
// (MSHR-merged -> no overfetch), register double-buffer, weights via LDS
// broadcast. One barrier total; 13KB LDS -> high natural occupancy.
__global__ __launch_bounds__(256) void scores_kernel(const float* __restrict__ X,
                                                     const float* __restrict__ w2,
                                                     const float* __restrict__ cvec,
                                                     float* __restrict__ sT,
                                                     int NLET) {
    __shared__ float4 wtile[32][LBL];   // [quad][label] : 13312 B

    const int tid    = threadIdx.x;
    const int letter = blockIdx.x * 256 + tid;

    const float4* W4 = (const float4*)w2;
    for (int i = tid; i < 32 * LBL; i += 256) {
        const int l = i >> 5, q = i & 31;
        wtile[q][l] = W4[i];
    }
    __syncthreads();

    const float4* xr = (const float4*)X + (size_t)letter * 32;

    float acc[LBL];
#pragma unroll
    for (int l = 0; l < LBL; ++l) acc[l] = cvec[l];   // uniform -> s_load

#define COMPUTE(g, C0, C1, C2, C3)                                         \
    {                                                                      \
        _Pragma("unroll")                                                  \
        for (int l = 0; l < LBL; ++l) {                                    \
            const float4 w0 = wtile[4 * (g) + 0][l];  /* broadcast */      \
            const float4 w1 = wtile[4 * (g) + 1][l];                       \
            const float4 w2v = wtile[4 * (g) + 2][l];                      \
            const float4 w3 = wtile[4 * (g) + 3][l];                       \
            float a = acc[l];                                              \
            a = fmaf(C0.x, w0.x, a); a = fmaf(C0.y, w0.y, a);              \
            a = fmaf(C0.z, w0.z, a); a = fmaf(C0.w, w0.w, a);              \
            a = fmaf(C1.x, w1.x, a); a = fmaf(C1.y, w1.y, a);              \
            a = fmaf(C1.z, w1.z, a); a = fmaf(C1.w, w1.w, a);              \
            a = fmaf(C2.x, w2v.x, a); a = fmaf(C2.y, w2v.y, a);            \
            a = fmaf(C2.z, w2v.z, a); a = fmaf(C2.w, w2v.w, a);            \
            a = fmaf(C3.x, w3.x, a); a = fmaf(C3.y, w3.y, a);              \
            a = fmaf(C3.z, w3.z, a); a = fmaf(C3.w, w3.w, a);              \
            acc[l] = a;                                                    \
        }                                                                  \
    }

    float4 c0 = xr[0], c1 = xr[1], c2 = xr[2], c3 = xr[3];
    for (int g = 0; g < 7; ++g) {      // NOT unrolled (r6 lesson)
        const float4 n0 = xr[4 * g + 4], n1 = xr[4 * g + 5];
        const float4 n2 = xr[4 * g + 6], n3 = xr[4 * g + 7];
        COMPUTE(g, c0, c1, c2, c3)
        c0 = n0; c1 = n1; c2 = n2; c3 = n3;
    }
    COMPUTE(7, c0, c1, c2, c3)
#undef COMPUTE

#pragma unroll
    for (int l = 0; l < LBL; ++l)
        sT[(size_t)l * NLET + letter] = acc[l];   // coalesced 256B/instr
}

// ---------------- kernel B: Viterbi decode (word-per-thread) ----------------
// Zero cross-lane traffic. i-outer/j-inner with strict '>' ascending i =
// exact first-occurrence argmax. T rows broadcast from LDS. Backpointers
// packed 4/byte in LDS. Emission row prefetched one step ahead.
// t-loop NOT unrolled (r7 lesson: unrolling -> register hoisting explosion).
__global__ __launch_bounds__(64) void viterbi_kernel(const float* __restrict__ sT,
                                                     const float* __restrict__ Tm,
                                                     int* __restrict__ out,
                                                     int NLET) {
    __shared__ float    T_lds[LBL][LBL];
    __shared__ unsigned bp_lds[64][MM - 1][7];   // 64 words x 13 steps x 26 bytes

    const int tid  = threadIdx.x;
    const int word = blockIdx.x * 64 + tid;
    const size_t base = (size_t)word * MM;

    for (int i = tid; i < LBL * LBL; i += 64)
        T_lds[i / LBL][i % LBL] = Tm[i];
    __syncthreads();

    float v[LBL], spre[LBL];
#pragma unroll
    for (int j = 0; j < LBL; ++j) v[j] = sT[(size_t)j * NLET + base];        // t=0
#pragma unroll
    for (int j = 0; j < LBL; ++j) spre[j] = sT[(size_t)j * NLET + base + 1]; // t=1

    for (int t = 1; t < MM; ++t) {      // NOT unrolled
        float vnew[LBL];
        int bp[LBL];
        {
            const float vi = v[0];
#pragma unroll
            for (int j = 0; j < LBL; ++j) { vnew[j] = vi + T_lds[0][j]; bp[j] = 0; }
        }
#pragma unroll
        for (int i = 1; i < LBL; ++i) {
            const float vi = v[i];
#pragma unroll
            for (int j = 0; j < LBL; ++j) {
                const float cand = vi + T_lds[i][j];     // broadcast read
                if (cand > vnew[j]) { vnew[j] = cand; bp[j] = i; }  // first-max wins
            }
        }
#pragma unroll
        for (int j = 0; j < LBL; ++j) v[j] = vnew[j] + spre[j];
        if (t + 1 < MM) {
#pragma unroll
            for (int j = 0; j < LBL; ++j)
                spre[j] = sT[(size_t)j * NLET + base + (t + 1)];   // prefetch
        }
        // pack backpointers 4-per-u32 into LDS
#pragma unroll
        for (int p = 0; p < 7; ++p) {
            unsigned w = 0;
#pragma unroll
            for (int bq = 0; bq < 4; ++bq) {
                const int j = p * 4 + bq;
                if (j < LBL) w |= ((unsigned)bp[j]) << (8 * bq);
            }
            bp_lds[tid][t - 1][p] = w;
        }
    }

    // final argmax over j (first occurrence)
    float best = v[0];
    int cur = 0;
#pragma unroll
    for (int j = 1; j < LBL; ++j)
        if (v[j] > best) { best = v[j]; cur = j; }

    out[base + (MM - 1)] = cur;
#pragma unroll
    for (int k = MM - 2; k >= 0; --k) {
        const unsigned pk = bp_lds[tid][k][cur >> 2];
        cur = (int)((pk >> ((cur & 3) * 8)) & 0xffu);
        out[base + k] = cur;
    }
}

// ---------------- fallback: round-2 fused kernel (used if d_ws too small) ----------------
__global__ __launch_bounds__(256) void crf_kernel(const float* __restrict__ X,
                                                  const float* __restrict__ T,
                                                  const float* __restrict__ w2,
                                                  const float* __restrict__ cvec,
                                                  int* __restrict__ out) {
    __shared__ float4 tile[LPB * 4];
    __shared__ float  s_lds[WPB * MM * LBL];
    __shared__ float  v_lds[WPB * 32];

    const int tid = threadIdx.x;
    const int blk = blockIdx.x;
    const float4* X4 = (const float4*)X + (size_t)blk * LPB * (FF / 4);
    const float4* W4 = (const float4*)w2;

    float acc[LBL];
    if (tid < LPB) {
#pragma unroll
        for (int l = 0; l < LBL; ++l) acc[l] = cvec[l];
    }
    const int c0 = tid, c1 = tid + 256, c2 = tid + 512, c3 = tid + 768;
    float4 st0, st1, st2, st3;
    st0 = X4[(c0 >> 2) * 32 + (c0 & 3)];
    st1 = X4[(c1 >> 2) * 32 + (c1 & 3)];
    st2 = X4[(c2 >> 2) * 32 + (c2 & 3)];
    if (tid < 128) st3 = X4[(c3 >> 2) * 32 + (c3 & 3)];

    for (int iter = 0; iter < NITER; ++iter) {
        tile[(c0 >> 2) * 4 + ((c0 & 3) ^ ((c0 >> 2) & 3))] = st0;
        tile[(c1 >> 2) * 4 + ((c1 & 3) ^ ((c1 >> 2) & 3))] = st1;
        tile[(c2 >> 2) * 4 + ((c2 & 3) ^ ((c2 >> 2) & 3))] = st2;
        if (tid < 128) tile[(c3 >> 2) * 4 + ((c3 & 3) ^ ((c3 >> 2) & 3))] = st3;
        __syncthreads();
        if (iter + 1 < NITER) {
            const int ofs = (iter + 1) * 4;
            st0 = X4[(c0 >> 2) * 32 + ofs + (c0 & 3)];
            st1 = X4[(c1 >> 2) * 32 + ofs + (c1 & 3)];
            st2 = X4[(c2 >> 2) * 32 + ofs + (c2 & 3)];
            if (tid < 128) st3 = X4[(c3 >> 2) * 32 + ofs + (c3 & 3)];
        }
        if (tid < LPB) {
            const float4 xv0 = tile[tid * 4 + (0 ^ (tid & 3))];
            const float4 xv1 = tile[tid * 4 + (1 ^ (tid & 3))];
            const float4 xv2 = tile[tid * 4 + (2 ^ (tid & 3))];
            const float4 xv3 = tile[tid * 4 + (3 ^ (tid & 3))];
#pragma unroll
            for (int l = 0; l < LBL; ++l) {
                const float4 w0 = W4[l * 32 + iter * 4 + 0];
                const float4 w1 = W4[l * 32 + iter * 4 + 1];
                const float4 w2v = W4[l * 32 + iter * 4 + 2];
                const float4 w3 = W4[l * 32 + iter * 4 + 3];
                float a = acc[l];
                a = fmaf(xv0.x, w0.x, a); a = fmaf(xv0.y, w0.y, a);
                a = fmaf(xv0.z, w0.z, a); a = fmaf(xv0.w, w0.w, a);
                a = fmaf(xv1.x, w1.x, a); a = fmaf(xv1.y, w1.y, a);
                a = fmaf(xv1.z, w1.z, a); a = fmaf(xv1.w, w1.w, a);
                a = fmaf(xv2.x, w2v.x, a); a = fmaf(xv2.y, w2v.y, a);
                a = fmaf(xv2.z, w2v.z, a); a = fmaf(xv2.w, w2v.w, a);
                a = fmaf(xv3.x, w3.x, a); a = fmaf(xv3.y, w3.y, a);
                a = fmaf(xv3.z, w3.z, a); a = fmaf(xv3.w, w3.w, a);
                acc[l] = a;
            }
        }
        __syncthreads();
    }
    if (tid < LPB) {
#pragma unroll
        for (int l = 0; l < LBL; ++l) s_lds[tid * LBL + l] = acc[l];
    }
    __syncthreads();

    const int lane = tid & 63;
    const int wvid = tid >> 6;
    const int half = lane >> 5;
    const int j = lane & 31;
    const int jc = (j < LBL) ? j : 0;

    float tcol[LBL];
#pragma unroll
    for (int i = 0; i < LBL; ++i) tcol[i] = T[i * LBL + jc];

    for (int pass = 0; pass < 2; ++pass) {
        const int wi = pass * 8 + wvid * 2 + half;
        const int word = blk * WPB + wi;
        const float* sw = s_lds + wi * MM * LBL;
        float* vbp = v_lds + wi * 32;

        float v = (j < LBL) ? sw[j] : -INFINITY;
        if (j < LBL) vbp[j] = v;
        unsigned bp_pack[4] = {0u, 0u, 0u, 0u};

#pragma unroll
        for (int t = 1; t < MM; ++t) {
            float best = -INFINITY;
            int bi = 0;
#define VCHK(vexpr, idx) { const float val = (vexpr) + tcol[idx]; \
                           if (val > best) { best = val; bi = idx; } }
            {
                float4 vv;
                vv = *(const float4*)(vbp + 0);
                VCHK(vv.x, 0) VCHK(vv.y, 1) VCHK(vv.z, 2) VCHK(vv.w, 3)
                vv = *(const float4*)(vbp + 4);
                VCHK(vv.x, 4) VCHK(vv.y, 5) VCHK(vv.z, 6) VCHK(vv.w, 7)
                vv = *(const float4*)(vbp + 8);
                VCHK(vv.x, 8) VCHK(vv.y, 9) VCHK(vv.z, 10) VCHK(vv.w, 11)
                vv = *(const float4*)(vbp + 12);
                VCHK(vv.x, 12) VCHK(vv.y, 13) VCHK(vv.z, 14) VCHK(vv.w, 15)
                vv = *(const float4*)(vbp + 16);
                VCHK(vv.x, 16) VCHK(vv.y, 17) VCHK(vv.z, 18) VCHK(vv.w, 19)
                vv = *(const float4*)(vbp + 20);
                VCHK(vv.x, 20) VCHK(vv.y, 21) VCHK(vv.z, 22) VCHK(vv.w, 23)
                vv = *(const float4*)(vbp + 24);
                VCHK(vv.x, 24) VCHK(vv.y, 25)
            }
#undef VCHK
            v = (j < LBL) ? (best + sw[t * LBL + j]) : -INFINITY;
            if (j < LBL) vbp[j] = v;
            const int k = t - 1;
            bp_pack[k >> 2] |= (unsigned)bi << ((k & 3) * 8);
        }

        float best = v;
        int bidx = (j < LBL) ? j : 999;
#pragma unroll
        for (int d = 1; d < 32; d <<= 1) {
            const float ov = __shfl_xor(best, d, 64);
            const int oi = __shfl_xor(bidx, d, 64);
            if (ov > best || (ov == best && oi < bidx)) { best = ov; bidx = oi; }
        }
        int cur = bidx;
        if (j == 0) out[word * MM + (MM - 1)] = cur;
#pragma unroll
        for (int k = MM - 2; k >= 0; --k) {
            const unsigned packed = __shfl(bp_pack[k >> 2], (lane & 32) | cur, 64);
            cur = (int)((packed >> ((k & 3) * 8)) & 0xffu);
            if (j == 0) out[word * MM + k] = cur;
        }
        __syncthreads();
    }
}

extern "C" void kernel_launch(void* const* d_in, const int* in_sizes, int n_in,
                              void* d_out, int out_size, void* d_ws, size_t ws_size,
                              hipStream_t stream) {
    const float* X = (const float*)d_in[0];
    const float* K = (const float*)d_in[1];
    const float* b = (const float*)d_in[2];
    const float* W = (const float*)d_in[3];
    const float* T = (const float*)d_in[4];
    int* out = (int*)d_out;

    const int nw = in_sizes[0] / (MM * FF);     // 32768 words
    const int NLET = nw * MM;                   // 458752 letters

    const size_t sT_bytes = (size_t)LBL * NLET * sizeof(float);   // ~47.7 MB
    const size_t w_bytes  = (size_t)(LBL * FF + LBL) * sizeof(float);

    if (ws_size >= sT_bytes + w_bytes && (NLET % 256) == 0 && (nw % 64) == 0) {
        float* sT   = (float*)d_ws;
        float* w2   = (float*)((char*)d_ws + sT_bytes);
        float* cvec = w2 + LBL * FF;
        prep_kernel<<<(LBL * FF + 255) / 256, 256, 0, stream>>>(K, b, W, w2, cvec);
        scores_kernel<<<NLET / 256, 256, 0, stream>>>(X, w2, cvec, sT, NLET);
        viterbi_kernel<<<nw / 64, 64, 0, stream>>>(sT, T, out, NLET);
    } else {
        float* w2   = (float*)d_ws;
        float* cvec = w2 + LBL * FF;
        prep_kernel<<<(LBL * FF + 255) / 256, 256, 0, stream>>>(K, b, W, w2, cvec);
        crf_kernel<<<nw / WPB, 256, 0, stream>>>(X, T, w2, cvec, out);
    }
}

// Round 9
// 252.529 us; speedup vs baseline: 6.9224x; 1.0630x over previous
//
#include <hip/hip_runtime.h>
#include <math.h>

#define LBL 26
#define MM  14
#define FF  128
#define HH  16
#define WW  8
#define KSZ 5
#define WPB 16              // words per block (fused fallback)
#define LPB (WPB * MM)      // 224
#define NITER 8

// ---------------- kernel 1: fold conv into emission weights ----------------
__global__ void prep_kernel(const float* __restrict__ K,
                            const float* __restrict__ b,
                            const float* __restrict__ W,
                            float* __restrict__ w2,
                            float* __restrict__ cvec) {
    int idx = blockIdx.x * blockDim.x + threadIdx.x;
    int stride = gridDim.x * blockDim.x;
    for (int o = idx; o < LBL * FF; o += stride) {
        int l = o / FF, f = o % FF;
        int qy = f / WW, qx = f % WW;
        double acc = 0.0;
        for (int ky = 0; ky < KSZ; ++ky) {
            int y = qy - ky + 2;
            if (y < 0 || y >= HH) continue;
            for (int kx = 0; kx < KSZ; ++kx) {
                int x = qx - kx + 2;
                if (x < 0 || x >= WW) continue;
                acc += (double)K[ky * KSZ + kx] * (double)W[l * FF + y * WW + x];
            }
        }
        w2[o] = (float)acc;
    }
    for (int l = idx; l < LBL; l += stride) {
        double s = 0.0;
        for (int f = 0; f < FF; ++f) s += (double)W[l * FF + f];
        cvec[l] = (float)(s * (double)b[0]);
    }
}

// ---------------- kernel A: emission scores (register-staged, word-major out) ----------------
// Thread = one letter, X row as 8 back-to-back float4 groups (line-complete),
// weights via LDS broadcast. Output sV[letter][0..PAD) (= sV[word][t][l]),
// repacked through LDS so the global write is coalesced.
template <int PAD>
__global__ __launch_bounds__(256) void scores_kernel(const float* __restrict__ X,
                                                     const float* __restrict__ w2,
                                                     const float* __restrict__ cvec,
                                                     float* __restrict__ sV) {
    __shared__ float4 wtile[32][LBL];      // [quad][label] : 13312 B
    __shared__ float  slds[256 * LBL];     // repack slab    : 26624 B

    const int tid    = threadIdx.x;
    const int letter = blockIdx.x * 256 + tid;

    const float4* W4 = (const float4*)w2;
    for (int i = tid; i < 32 * LBL; i += 256) {
        const int l = i >> 5, q = i & 31;
        wtile[q][l] = W4[i];
    }
    __syncthreads();

    const float4* xr = (const float4*)X + (size_t)letter * 32;

    float acc[LBL];
#pragma unroll
    for (int l = 0; l < LBL; ++l) acc[l] = cvec[l];   // uniform -> s_load

#define COMPUTE(g, C0, C1, C2, C3)                                         \
    {                                                                      \
        _Pragma("unroll")                                                  \
        for (int l = 0; l < LBL; ++l) {                                    \
            const float4 w0 = wtile[4 * (g) + 0][l];  /* broadcast */      \
            const float4 w1 = wtile[4 * (g) + 1][l];                       \
            const float4 w2v = wtile[4 * (g) + 2][l];                      \
            const float4 w3 = wtile[4 * (g) + 3][l];                       \
            float a = acc[l];                                              \
            a = fmaf(C0.x, w0.x, a); a = fmaf(C0.y, w0.y, a);              \
            a = fmaf(C0.z, w0.z, a); a = fmaf(C0.w, w0.w, a);              \
            a = fmaf(C1.x, w1.x, a); a = fmaf(C1.y, w1.y, a);              \
            a = fmaf(C1.z, w1.z, a); a = fmaf(C1.w, w1.w, a);              \
            a = fmaf(C2.x, w2v.x, a); a = fmaf(C2.y, w2v.y, a);            \
            a = fmaf(C2.z, w2v.z, a); a = fmaf(C2.w, w2v.w, a);            \
            a = fmaf(C3.x, w3.x, a); a = fmaf(C3.y, w3.y, a);              \
            a = fmaf(C3.z, w3.z, a); a = fmaf(C3.w, w3.w, a);              \
            acc[l] = a;                                                    \
        }                                                                  \
    }

    float4 c0 = xr[0], c1 = xr[1], c2 = xr[2], c3 = xr[3];
    for (int g = 0; g < 7; ++g) {      // NOT unrolled (r6 lesson)
        const float4 n0 = xr[4 * g + 4], n1 = xr[4 * g + 5];
        const float4 n2 = xr[4 * g + 6], n3 = xr[4 * g + 7];
        COMPUTE(g, c0, c1, c2, c3)
        c0 = n0; c1 = n1; c2 = n2; c3 = n3;
    }
    COMPUTE(7, c0, c1, c2, c3)
#undef COMPUTE

    // repack: LDS slab then coalesced word-major write (letter*PAD + l)
#pragma unroll
    for (int l = 0; l < LBL; ++l) slds[tid * LBL + l] = acc[l];
    __syncthreads();
    const size_t obase = (size_t)blockIdx.x * 256 * PAD;
    for (int idx = tid; idx < 256 * PAD; idx += 256) {
        const int ll = idx / PAD, lw = idx - ll * PAD;
        sV[obase + idx] = (lw < LBL) ? slds[ll * LBL + lw] : 0.0f;
    }
}

// ---------------- kernel B: Viterbi decode (word-per-thread, word-major scores) ----------------
// Per-thread contiguous, 16B-aligned (PAD=28) row reads + next-step prefetch.
// i-outer/j-inner strict '>' = exact first-occurrence argmax. T broadcast
// from LDS; backpointers packed 4/byte in LDS. t-loop NOT unrolled (r7 lesson).
template <int PAD>
__global__ __launch_bounds__(64) void viterbi_kernel(const float* __restrict__ sV,
                                                     const float* __restrict__ Tm,
                                                     int* __restrict__ out) {
    __shared__ float    T_lds[LBL][LBL];
    __shared__ unsigned bp_lds[64][MM - 1][7];   // 64 words x 13 steps x 26 bytes

    const int tid  = threadIdx.x;
    const int word = blockIdx.x * 64 + tid;
    const float* sw = sV + (size_t)word * (MM * PAD);
    const size_t base = (size_t)word * MM;

    for (int i = tid; i < LBL * LBL; i += 64)
        T_lds[i / LBL][i % LBL] = Tm[i];
    __syncthreads();

    float v[LBL], spre[LBL];
#pragma unroll
    for (int j = 0; j < LBL; ++j) v[j] = sw[j];             // t=0 row
#pragma unroll
    for (int j = 0; j < LBL; ++j) spre[j] = sw[PAD + j];    // t=1 row

    for (int t = 1; t < MM; ++t) {      // NOT unrolled
        float vnew[LBL];
        int bp[LBL];
        {
            const float vi = v[0];
#pragma unroll
            for (int j = 0; j < LBL; ++j) { vnew[j] = vi + T_lds[0][j]; bp[j] = 0; }
        }
#pragma unroll
        for (int i = 1; i < LBL; ++i) {
            const float vi = v[i];
#pragma unroll
            for (int j = 0; j < LBL; ++j) {
                const float cand = vi + T_lds[i][j];     // broadcast read
                if (cand > vnew[j]) { vnew[j] = cand; bp[j] = i; }  // first-max wins
            }
        }
#pragma unroll
        for (int j = 0; j < LBL; ++j) v[j] = vnew[j] + spre[j];
        if (t + 1 < MM) {
            const float* nxt = sw + (size_t)(t + 1) * PAD;
#pragma unroll
            for (int j = 0; j < LBL; ++j) spre[j] = nxt[j];   // contiguous prefetch
        }
#pragma unroll
        for (int p = 0; p < 7; ++p) {
            unsigned w = 0;
#pragma unroll
            for (int bq = 0; bq < 4; ++bq) {
                const int j = p * 4 + bq;
                if (j < LBL) w |= ((unsigned)bp[j]) << (8 * bq);
            }
            bp_lds[tid][t - 1][p] = w;
        }
    }

    // final argmax over j (first occurrence)
    float best = v[0];
    int cur = 0;
#pragma unroll
    for (int j = 1; j < LBL; ++j)
        if (v[j] > best) { best = v[j]; cur = j; }

    out[base + (MM - 1)] = cur;
#pragma unroll
    for (int k = MM - 2; k >= 0; --k) {
        const unsigned pk = bp_lds[tid][k][cur >> 2];
        cur = (int)((pk >> ((cur & 3) * 8)) & 0xffu);
        out[base + k] = cur;
    }
}

// ---------------- fallback: round-2 fused kernel (used if d_ws too small) ----------------
__global__ __launch_bounds__(256) void crf_kernel(const float* __restrict__ X,
                                                  const float* __restrict__ T,
                                                  const float* __restrict__ w2,
                                                  const float* __restrict__ cvec,
                                                  int* __restrict__ out) {
    __shared__ float4 tile[LPB * 4];
    __shared__ float  s_lds[WPB * MM * LBL];
    __shared__ float  v_lds[WPB * 32];

    const int tid = threadIdx.x;
    const int blk = blockIdx.x;
    const float4* X4 = (const float4*)X + (size_t)blk * LPB * (FF / 4);
    const float4* W4 = (const float4*)w2;

    float acc[LBL];
    if (tid < LPB) {
#pragma unroll
        for (int l = 0; l < LBL; ++l) acc[l] = cvec[l];
    }
    const int c0 = tid, c1 = tid + 256, c2 = tid + 512, c3 = tid + 768;
    float4 st0, st1, st2, st3;
    st0 = X4[(c0 >> 2) * 32 + (c0 & 3)];
    st1 = X4[(c1 >> 2) * 32 + (c1 & 3)];
    st2 = X4[(c2 >> 2) * 32 + (c2 & 3)];
    if (tid < 128) st3 = X4[(c3 >> 2) * 32 + (c3 & 3)];

    for (int iter = 0; iter < NITER; ++iter) {
        tile[(c0 >> 2) * 4 + ((c0 & 3) ^ ((c0 >> 2) & 3))] = st0;
        tile[(c1 >> 2) * 4 + ((c1 & 3) ^ ((c1 >> 2) & 3))] = st1;
        tile[(c2 >> 2) * 4 + ((c2 & 3) ^ ((c2 >> 2) & 3))] = st2;
        if (tid < 128) tile[(c3 >> 2) * 4 + ((c3 & 3) ^ ((c3 >> 2) & 3))] = st3;
        __syncthreads();
        if (iter + 1 < NITER) {
            const int ofs = (iter + 1) * 4;
            st0 = X4[(c0 >> 2) * 32 + ofs + (c0 & 3)];
            st1 = X4[(c1 >> 2) * 32 + ofs + (c1 & 3)];
            st2 = X4[(c2 >> 2) * 32 + ofs + (c2 & 3)];
            if (tid < 128) st3 = X4[(c3 >> 2) * 32 + ofs + (c3 & 3)];
        }
        if (tid < LPB) {
            const float4 xv0 = tile[tid * 4 + (0 ^ (tid & 3))];
            const float4 xv1 = tile[tid * 4 + (1 ^ (tid & 3))];
            const float4 xv2 = tile[tid * 4 + (2 ^ (tid & 3))];
            const float4 xv3 = tile[tid * 4 + (3 ^ (tid & 3))];
#pragma unroll
            for (int l = 0; l < LBL; ++l) {
                const float4 w0 = W4[l * 32 + iter * 4 + 0];
                const float4 w1 = W4[l * 32 + iter * 4 + 1];
                const float4 w2v = W4[l * 32 + iter * 4 + 2];
                const float4 w3 = W4[l * 32 + iter * 4 + 3];
                float a = acc[l];
                a = fmaf(xv0.x, w0.x, a); a = fmaf(xv0.y, w0.y, a);
                a = fmaf(xv0.z, w0.z, a); a = fmaf(xv0.w, w0.w, a);
                a = fmaf(xv1.x, w1.x, a); a = fmaf(xv1.y, w1.y, a);
                a = fmaf(xv1.z, w1.z, a); a = fmaf(xv1.w, w1.w, a);
                a = fmaf(xv2.x, w2v.x, a); a = fmaf(xv2.y, w2v.y, a);
                a = fmaf(xv2.z, w2v.z, a); a = fmaf(xv2.w, w2v.w, a);
                a = fmaf(xv3.x, w3.x, a); a = fmaf(xv3.y, w3.y, a);
                a = fmaf(xv3.z, w3.z, a); a = fmaf(xv3.w, w3.w, a);
                acc[l] = a;
            }
        }
        __syncthreads();
    }
    if (tid < LPB) {
#pragma unroll
        for (int l = 0; l < LBL; ++l) s_lds[tid * LBL + l] = acc[l];
    }
    __syncthreads();

    const int lane = tid & 63;
    const int wvid = tid >> 6;
    const int half = lane >> 5;
    const int j = lane & 31;
    const int jc = (j < LBL) ? j : 0;

    float tcol[LBL];
#pragma unroll
    for (int i = 0; i < LBL; ++i) tcol[i] = T[i * LBL + jc];

    for (int pass = 0; pass < 2; ++pass) {
        const int wi = pass * 8 + wvid * 2 + half;
        const int word = blk * WPB + wi;
        const float* sw = s_lds + wi * MM * LBL;
        float* vbp = v_lds + wi * 32;

        float v = (j < LBL) ? sw[j] : -INFINITY;
        if (j < LBL) vbp[j] = v;
        unsigned bp_pack[4] = {0u, 0u, 0u, 0u};

#pragma unroll
        for (int t = 1; t < MM; ++t) {
            float best = -INFINITY;
            int bi = 0;
#define VCHK(vexpr, idx) { const float val = (vexpr) + tcol[idx]; \
                           if (val > best) { best = val; bi = idx; } }
            {
                float4 vv;
                vv = *(const float4*)(vbp + 0);
                VCHK(vv.x, 0) VCHK(vv.y, 1) VCHK(vv.z, 2) VCHK(vv.w, 3)
                vv = *(const float4*)(vbp + 4);
                VCHK(vv.x, 4) VCHK(vv.y, 5) VCHK(vv.z, 6) VCHK(vv.w, 7)
                vv = *(const float4*)(vbp + 8);
                VCHK(vv.x, 8) VCHK(vv.y, 9) VCHK(vv.z, 10) VCHK(vv.w, 11)
                vv = *(const float4*)(vbp + 12);
                VCHK(vv.x, 12) VCHK(vv.y, 13) VCHK(vv.z, 14) VCHK(vv.w, 15)
                vv = *(const float4*)(vbp + 16);
                VCHK(vv.x, 16) VCHK(vv.y, 17) VCHK(vv.z, 18) VCHK(vv.w, 19)
                vv = *(const float4*)(vbp + 20);
                VCHK(vv.x, 20) VCHK(vv.y, 21) VCHK(vv.z, 22) VCHK(vv.w, 23)
                vv = *(const float4*)(vbp + 24);
                VCHK(vv.x, 24) VCHK(vv.y, 25)
            }
#undef VCHK
            v = (j < LBL) ? (best + sw[t * LBL + j]) : -INFINITY;
            if (j < LBL) vbp[j] = v;
            const int k = t - 1;
            bp_pack[k >> 2] |= (unsigned)bi << ((k & 3) * 8);
        }

        float best = v;
        int bidx = (j < LBL) ? j : 999;
#pragma unroll
        for (int d = 1; d < 32; d <<= 1) {
            const float ov = __shfl_xor(best, d, 64);
            const int oi = __shfl_xor(bidx, d, 64);
            if (ov > best || (ov == best && oi < bidx)) { best = ov; bidx = oi; }
        }
        int cur = bidx;
        if (j == 0) out[word * MM + (MM - 1)] = cur;
#pragma unroll
        for (int k = MM - 2; k >= 0; --k) {
            const unsigned packed = __shfl(bp_pack[k >> 2], (lane & 32) | cur, 64);
            cur = (int)((packed >> ((k & 3) * 8)) & 0xffu);
            if (j == 0) out[word * MM + k] = cur;
        }
        __syncthreads();
    }
}

extern "C" void kernel_launch(void* const* d_in, const int* in_sizes, int n_in,
                              void* d_out, int out_size, void* d_ws, size_t ws_size,
                              hipStream_t stream) {
    const float* X = (const float*)d_in[0];
    const float* K = (const float*)d_in[1];
    const float* b = (const float*)d_in[2];
    const float* W = (const float*)d_in[3];
    const float* T = (const float*)d_in[4];
    int* out = (int*)d_out;

    const int nw = in_sizes[0] / (MM * FF);     // 32768 words
    const int NLET = nw * MM;                   // 458752 letters

    const size_t w_bytes = (size_t)(LBL * FF + LBL) * sizeof(float);
    const size_t sV28    = (size_t)NLET * 28 * sizeof(float);   // ~51.4 MB
    const size_t sV26    = (size_t)NLET * 26 * sizeof(float);   // ~47.7 MB

    const bool shape_ok = (NLET % 256) == 0 && (nw % 64) == 0;

    if (shape_ok && ws_size >= sV28 + w_bytes) {
        float* sV   = (float*)d_ws;
        float* w2   = (float*)((char*)d_ws + sV28);
        float* cvec = w2 + LBL * FF;
        prep_kernel<<<(LBL * FF + 255) / 256, 256, 0, stream>>>(K, b, W, w2, cvec);
        scores_kernel<28><<<NLET / 256, 256, 0, stream>>>(X, w2, cvec, sV);
        viterbi_kernel<28><<<nw / 64, 64, 0, stream>>>(sV, T, out);
    } else if (shape_ok && ws_size >= sV26 + w_bytes) {
        float* sV   = (float*)d_ws;
        float* w2   = (float*)((char*)d_ws + sV26);
        float* cvec = w2 + LBL * FF;
        prep_kernel<<<(LBL * FF + 255) / 256, 256, 0, stream>>>(K, b, W, w2, cvec);
        scores_kernel<26><<<NLET / 256, 256, 0, stream>>>(X, w2, cvec, sV);
        viterbi_kernel<26><<<nw / 64, 64, 0, stream>>>(sV, T, out);
    } else {
        float* w2   = (float*)d_ws;
        float* cvec = w2 + LBL * FF;
        prep_kernel<<<(LBL * FF + 255) / 256, 256, 0, stream>>>(K, b, W, w2, cvec);
        crf_kernel<<<nw / WPB, 256, 0, stream>>>(X, T, w2, cvec, out);
    }
}

// Round 10
// 147.728 us; speedup vs baseline: 11.8334x; 1.7094x over previous
//
#include <hip/hip_runtime.h>
#include <math.h>

#define LBL 26
#define MM  14
#define FF  128
#define HH  16
#define WW  8
#define KSZ 5
#define WPB 16              // words per block (fused fallback)
#define LPB (WPB * MM)      // 224
#define NITER 8

// ---------------- kernel 1: fold conv into emission weights ----------------
__global__ void prep_kernel(const float* __restrict__ K,
                            const float* __restrict__ b,
                            const float* __restrict__ W,
                            float* __restrict__ w2,
                            float* __restrict__ cvec) {
    int idx = blockIdx.x * blockDim.x + threadIdx.x;
    int stride = gridDim.x * blockDim.x;
    for (int o = idx; o < LBL * FF; o += stride) {
        int l = o / FF, f = o % FF;
        int qy = f / WW, qx = f % WW;
        double acc = 0.0;
        for (int ky = 0; ky < KSZ; ++ky) {
            int y = qy - ky + 2;
            if (y < 0 || y >= HH) continue;
            for (int kx = 0; kx < KSZ; ++kx) {
                int x = qx - kx + 2;
                if (x < 0 || x >= WW) continue;
                acc += (double)K[ky * KSZ + kx] * (double)W[l * FF + y * WW + x];
            }
        }
        w2[o] = (float)acc;
    }
    for (int l = idx; l < LBL; l += stride) {
        double s = 0.0;
        for (int f = 0; f < FF; ++f) s += (double)W[l * FF + f];
        cvec[l] = (float)(s * (double)b[0]);
    }
}

// ---------------- kernel A: emission scores (register-staged, word-major out) ----------------
// Thread = one letter, X row as 8 back-to-back float4 groups (line-complete),
// weights via LDS broadcast. Output sV[letter][0..PAD) (= sV[word][t][l]),
// repacked through LDS so the global write is coalesced. (r8/r9 proven, ~70us)
template <int PAD>
__global__ __launch_bounds__(256) void scores_kernel(const float* __restrict__ X,
                                                     const float* __restrict__ w2,
                                                     const float* __restrict__ cvec,
                                                     float* __restrict__ sV) {
    __shared__ float4 wtile[32][LBL];      // [quad][label] : 13312 B
    __shared__ float  slds[256 * LBL];     // repack slab    : 26624 B

    const int tid    = threadIdx.x;
    const int letter = blockIdx.x * 256 + tid;

    const float4* W4 = (const float4*)w2;
    for (int i = tid; i < 32 * LBL; i += 256) {
        const int l = i >> 5, q = i & 31;
        wtile[q][l] = W4[i];
    }
    __syncthreads();

    const float4* xr = (const float4*)X + (size_t)letter * 32;

    float acc[LBL];
#pragma unroll
    for (int l = 0; l < LBL; ++l) acc[l] = cvec[l];   // uniform -> s_load

#define COMPUTE(g, C0, C1, C2, C3)                                         \
    {                                                                      \
        _Pragma("unroll")                                                  \
        for (int l = 0; l < LBL; ++l) {                                    \
            const float4 w0 = wtile[4 * (g) + 0][l];  /* broadcast */      \
            const float4 w1 = wtile[4 * (g) + 1][l];                       \
            const float4 w2v = wtile[4 * (g) + 2][l];                      \
            const float4 w3 = wtile[4 * (g) + 3][l];                       \
            float a = acc[l];                                              \
            a = fmaf(C0.x, w0.x, a); a = fmaf(C0.y, w0.y, a);              \
            a = fmaf(C0.z, w0.z, a); a = fmaf(C0.w, w0.w, a);              \
            a = fmaf(C1.x, w1.x, a); a = fmaf(C1.y, w1.y, a);              \
            a = fmaf(C1.z, w1.z, a); a = fmaf(C1.w, w1.w, a);              \
            a = fmaf(C2.x, w2v.x, a); a = fmaf(C2.y, w2v.y, a);            \
            a = fmaf(C2.z, w2v.z, a); a = fmaf(C2.w, w2v.w, a);            \
            a = fmaf(C3.x, w3.x, a); a = fmaf(C3.y, w3.y, a);              \
            a = fmaf(C3.z, w3.z, a); a = fmaf(C3.w, w3.w, a);              \
            acc[l] = a;                                                    \
        }                                                                  \
    }

    float4 c0 = xr[0], c1 = xr[1], c2 = xr[2], c3 = xr[3];
    for (int g = 0; g < 7; ++g) {      // NOT unrolled (r6 lesson)
        const float4 n0 = xr[4 * g + 4], n1 = xr[4 * g + 5];
        const float4 n2 = xr[4 * g + 6], n3 = xr[4 * g + 7];
        COMPUTE(g, c0, c1, c2, c3)
        c0 = n0; c1 = n1; c2 = n2; c3 = n3;
    }
    COMPUTE(7, c0, c1, c2, c3)
#undef COMPUTE

    // repack: LDS slab then coalesced word-major write (letter*PAD + l)
#pragma unroll
    for (int l = 0; l < LBL; ++l) slds[tid * LBL + l] = acc[l];
    __syncthreads();
    const size_t obase = (size_t)blockIdx.x * 256 * PAD;
    for (int idx = tid; idx < 256 * PAD; idx += 256) {
        const int ll = idx / PAD, lw = idx - ll * PAD;
        sV[obase + idx] = (lw < LBL) ? slds[ll * LBL + lw] : 0.0f;
    }
}

// ---------------- kernel B: Viterbi decode (j-per-lane, word-major scores) ----------------
// 32 lanes per word (j = label lane), 2 words/wave, 8 words per 256-block.
// Emission read per step = one coalesced 128B segment (word-major sV).
// vb row exchanged via wave-internal LDS (no barriers after T staging).
// ~48 VGPR (r2 structure) -> high occupancy; grid = nw/8 = 4096 blocks.
template <int PAD>
__global__ __launch_bounds__(256) void viterbi_kernel(const float* __restrict__ sV,
                                                      const float* __restrict__ Tm,
                                                      int* __restrict__ out) {
    __shared__ float T_lds[LBL * LBL];
    __shared__ float vb[8][32];

    const int tid  = threadIdx.x;
    for (int i = tid; i < LBL * LBL; i += 256) T_lds[i] = Tm[i];
    __syncthreads();

    const int wv   = tid >> 6;
    const int lane = tid & 63;
    const int half = lane >> 5;
    const int j    = lane & 31;
    const int jc   = (j < LBL) ? j : 25;         // clamped for safe reads

    const int wl   = wv * 2 + half;              // word slot in block
    const int word = blockIdx.x * 8 + wl;
    const float* sw = sV + (size_t)word * (MM * PAD);

    float tcol[LBL];                             // T[:, j]
#pragma unroll
    for (int i = 0; i < LBL; ++i) tcol[i] = T_lds[i * LBL + jc];

    float* vbw = &vb[wl][0];
    float v = (j < LBL) ? sw[j] : -INFINITY;
    vbw[j] = v;                                  // lanes 26..31 hold -inf (never read as i)
    unsigned bp_pack[4] = {0u, 0u, 0u, 0u};

#pragma unroll
    for (int t = 1; t < MM; ++t) {
        const float se = sw[t * PAD + jc];       // coalesced; issued early
        float best = -INFINITY;
        int bi = 0;
        const float4* q4 = (const float4*)vbw;   // broadcast reads (2 addrs/wave)
#define VCHK(vexpr, idx) { const float val = (vexpr) + tcol[idx]; \
                           if (val > best) { best = val; bi = idx; } }
        {
            float4 qq;
            qq = q4[0]; VCHK(qq.x, 0) VCHK(qq.y, 1) VCHK(qq.z, 2) VCHK(qq.w, 3)
            qq = q4[1]; VCHK(qq.x, 4) VCHK(qq.y, 5) VCHK(qq.z, 6) VCHK(qq.w, 7)
            qq = q4[2]; VCHK(qq.x, 8) VCHK(qq.y, 9) VCHK(qq.z, 10) VCHK(qq.w, 11)
            qq = q4[3]; VCHK(qq.x, 12) VCHK(qq.y, 13) VCHK(qq.z, 14) VCHK(qq.w, 15)
            qq = q4[4]; VCHK(qq.x, 16) VCHK(qq.y, 17) VCHK(qq.z, 18) VCHK(qq.w, 19)
            qq = q4[5]; VCHK(qq.x, 20) VCHK(qq.y, 21) VCHK(qq.z, 22) VCHK(qq.w, 23)
            qq = q4[6]; VCHK(qq.x, 24) VCHK(qq.y, 25)
        }
#undef VCHK
        v = (j < LBL) ? (best + se) : -INFINITY;
        vbw[j] = v;
        const int k = t - 1;
        bp_pack[k >> 2] |= (unsigned)bi << ((k & 3) * 8);
    }

    // argmax over j of final v (within 32-lane half), first occurrence
    float best = v;
    int bidx = (j < LBL) ? j : 999;
#pragma unroll
    for (int d = 1; d < 32; d <<= 1) {
        const float ov = __shfl_xor(best, d, 64);
        const int oi = __shfl_xor(bidx, d, 64);
        if (ov > best || (ov == best && oi < bidx)) { best = ov; bidx = oi; }
    }

    // backtrack (cur uniform within half; all lanes shuffle, lane j==0 stores)
    int cur = bidx;
    if (j == 0) out[word * MM + (MM - 1)] = cur;
#pragma unroll
    for (int k = MM - 2; k >= 0; --k) {
        const unsigned packed = __shfl(bp_pack[k >> 2], (lane & 32) | cur, 64);
        cur = (int)((packed >> ((k & 3) * 8)) & 0xffu);
        if (j == 0) out[word * MM + k] = cur;
    }
}

// ---------------- fallback: round-2 fused kernel (used if d_ws too small) ----------------
__global__ __launch_bounds__(256) void crf_kernel(const float* __restrict__ X,
                                                  const float* __restrict__ T,
                                                  const float* __restrict__ w2,
                                                  const float* __restrict__ cvec,
                                                  int* __restrict__ out) {
    __shared__ float4 tile[LPB * 4];
    __shared__ float  s_lds[WPB * MM * LBL];
    __shared__ float  v_lds[WPB * 32];

    const int tid = threadIdx.x;
    const int blk = blockIdx.x;
    const float4* X4 = (const float4*)X + (size_t)blk * LPB * (FF / 4);
    const float4* W4 = (const float4*)w2;

    float acc[LBL];
    if (tid < LPB) {
#pragma unroll
        for (int l = 0; l < LBL; ++l) acc[l] = cvec[l];
    }
    const int c0 = tid, c1 = tid + 256, c2 = tid + 512, c3 = tid + 768;
    float4 st0, st1, st2, st3;
    st0 = X4[(c0 >> 2) * 32 + (c0 & 3)];
    st1 = X4[(c1 >> 2) * 32 + (c1 & 3)];
    st2 = X4[(c2 >> 2) * 32 + (c2 & 3)];
    if (tid < 128) st3 = X4[(c3 >> 2) * 32 + (c3 & 3)];

    for (int iter = 0; iter < NITER; ++iter) {
        tile[(c0 >> 2) * 4 + ((c0 & 3) ^ ((c0 >> 2) & 3))] = st0;
        tile[(c1 >> 2) * 4 + ((c1 & 3) ^ ((c1 >> 2) & 3))] = st1;
        tile[(c2 >> 2) * 4 + ((c2 & 3) ^ ((c2 >> 2) & 3))] = st2;
        if (tid < 128) tile[(c3 >> 2) * 4 + ((c3 & 3) ^ ((c3 >> 2) & 3))] = st3;
        __syncthreads();
        if (iter + 1 < NITER) {
            const int ofs = (iter + 1) * 4;
            st0 = X4[(c0 >> 2) * 32 + ofs + (c0 & 3)];
            st1 = X4[(c1 >> 2) * 32 + ofs + (c1 & 3)];
            st2 = X4[(c2 >> 2) * 32 + ofs + (c2 & 3)];
            if (tid < 128) st3 = X4[(c3 >> 2) * 32 + ofs + (c3 & 3)];
        }
        if (tid < LPB) {
            const float4 xv0 = tile[tid * 4 + (0 ^ (tid & 3))];
            const float4 xv1 = tile[tid * 4 + (1 ^ (tid & 3))];
            const float4 xv2 = tile[tid * 4 + (2 ^ (tid & 3))];
            const float4 xv3 = tile[tid * 4 + (3 ^ (tid & 3))];
#pragma unroll
            for (int l = 0; l < LBL; ++l) {
                const float4 w0 = W4[l * 32 + iter * 4 + 0];
                const float4 w1 = W4[l * 32 + iter * 4 + 1];
                const float4 w2v = W4[l * 32 + iter * 4 + 2];
                const float4 w3 = W4[l * 32 + iter * 4 + 3];
                float a = acc[l];
                a = fmaf(xv0.x, w0.x, a); a = fmaf(xv0.y, w0.y, a);
                a = fmaf(xv0.z, w0.z, a); a = fmaf(xv0.w, w0.w, a);
                a = fmaf(xv1.x, w1.x, a); a = fmaf(xv1.y, w1.y, a);
                a = fmaf(xv1.z, w1.z, a); a = fmaf(xv1.w, w1.w, a);
                a = fmaf(xv2.x, w2v.x, a); a = fmaf(xv2.y, w2v.y, a);
                a = fmaf(xv2.z, w2v.z, a); a = fmaf(xv2.w, w2v.w, a);
                a = fmaf(xv3.x, w3.x, a); a = fmaf(xv3.y, w3.y, a);
                a = fmaf(xv3.z, w3.z, a); a = fmaf(xv3.w, w3.w, a);
                acc[l] = a;
            }
        }
        __syncthreads();
    }
    if (tid < LPB) {
#pragma unroll
        for (int l = 0; l < LBL; ++l) s_lds[tid * LBL + l] = acc[l];
    }
    __syncthreads();

    const int lane = tid & 63;
    const int wvid = tid >> 6;
    const int half = lane >> 5;
    const int j = lane & 31;
    const int jc = (j < LBL) ? j : 0;

    float tcol[LBL];
#pragma unroll
    for (int i = 0; i < LBL; ++i) tcol[i] = T[i * LBL + jc];

    for (int pass = 0; pass < 2; ++pass) {
        const int wi = pass * 8 + wvid * 2 + half;
        const int word = blk * WPB + wi;
        const float* sw = s_lds + wi * MM * LBL;
        float* vbp = v_lds + wi * 32;

        float v = (j < LBL) ? sw[j] : -INFINITY;
        if (j < LBL) vbp[j] = v;
        unsigned bp_pack[4] = {0u, 0u, 0u, 0u};

#pragma unroll
        for (int t = 1; t < MM; ++t) {
            float best = -INFINITY;
            int bi = 0;
#define VCHK(vexpr, idx) { const float val = (vexpr) + tcol[idx]; \
                           if (val > best) { best = val; bi = idx; } }
            {
                float4 vv;
                vv = *(const float4*)(vbp + 0);
                VCHK(vv.x, 0) VCHK(vv.y, 1) VCHK(vv.z, 2) VCHK(vv.w, 3)
                vv = *(const float4*)(vbp + 4);
                VCHK(vv.x, 4) VCHK(vv.y, 5) VCHK(vv.z, 6) VCHK(vv.w, 7)
                vv = *(const float4*)(vbp + 8);
                VCHK(vv.x, 8) VCHK(vv.y, 9) VCHK(vv.z, 10) VCHK(vv.w, 11)
                vv = *(const float4*)(vbp + 12);
                VCHK(vv.x, 12) VCHK(vv.y, 13) VCHK(vv.z, 14) VCHK(vv.w, 15)
                vv = *(const float4*)(vbp + 16);
                VCHK(vv.x, 16) VCHK(vv.y, 17) VCHK(vv.z, 18) VCHK(vv.w, 19)
                vv = *(const float4*)(vbp + 20);
                VCHK(vv.x, 20) VCHK(vv.y, 21) VCHK(vv.z, 22) VCHK(vv.w, 23)
                vv = *(const float4*)(vbp + 24);
                VCHK(vv.x, 24) VCHK(vv.y, 25)
            }
#undef VCHK
            v = (j < LBL) ? (best + sw[t * LBL + j]) : -INFINITY;
            if (j < LBL) vbp[j] = v;
            const int k = t - 1;
            bp_pack[k >> 2] |= (unsigned)bi << ((k & 3) * 8);
        }

        float best = v;
        int bidx = (j < LBL) ? j : 999;
#pragma unroll
        for (int d = 1; d < 32; d <<= 1) {
            const float ov = __shfl_xor(best, d, 64);
            const int oi = __shfl_xor(bidx, d, 64);
            if (ov > best || (ov == best && oi < bidx)) { best = ov; bidx = oi; }
        }
        int cur = bidx;
        if (j == 0) out[word * MM + (MM - 1)] = cur;
#pragma unroll
        for (int k = MM - 2; k >= 0; --k) {
            const unsigned packed = __shfl(bp_pack[k >> 2], (lane & 32) | cur, 64);
            cur = (int)((packed >> ((k & 3) * 8)) & 0xffu);
            if (j == 0) out[word * MM + k] = cur;
        }
        __syncthreads();
    }
}

extern "C" void kernel_launch(void* const* d_in, const int* in_sizes, int n_in,
                              void* d_out, int out_size, void* d_ws, size_t ws_size,
                              hipStream_t stream) {
    const float* X = (const float*)d_in[0];
    const float* K = (const float*)d_in[1];
    const float* b = (const float*)d_in[2];
    const float* W = (const float*)d_in[3];
    const float* T = (const float*)d_in[4];
    int* out = (int*)d_out;

    const int nw = in_sizes[0] / (MM * FF);     // 32768 words
    const int NLET = nw * MM;                   // 458752 letters

    const size_t w_bytes = (size_t)(LBL * FF + LBL) * sizeof(float);
    const size_t sV28    = (size_t)NLET * 28 * sizeof(float);   // ~51.4 MB
    const size_t sV26    = (size_t)NLET * 26 * sizeof(float);   // ~47.7 MB

    const bool shape_ok = (NLET % 256) == 0 && (nw % 8) == 0;

    if (shape_ok && ws_size >= sV28 + w_bytes) {
        float* sV   = (float*)d_ws;
        float* w2   = (float*)((char*)d_ws + sV28);
        float* cvec = w2 + LBL * FF;
        prep_kernel<<<(LBL * FF + 255) / 256, 256, 0, stream>>>(K, b, W, w2, cvec);
        scores_kernel<28><<<NLET / 256, 256, 0, stream>>>(X, w2, cvec, sV);
        viterbi_kernel<28><<<nw / 8, 256, 0, stream>>>(sV, T, out);
    } else if (shape_ok && ws_size >= sV26 + w_bytes) {
        float* sV   = (float*)d_ws;
        float* w2   = (float*)((char*)d_ws + sV26);
        float* cvec = w2 + LBL * FF;
        prep_kernel<<<(LBL * FF + 255) / 256, 256, 0, stream>>>(K, b, W, w2, cvec);
        scores_kernel<26><<<NLET / 256, 256, 0, stream>>>(X, w2, cvec, sV);
        viterbi_kernel<26><<<nw / 8, 256, 0, stream>>>(sV, T, out);
    } else {
        float* w2   = (float*)d_ws;
        float* cvec = w2 + LBL * FF;
        prep_kernel<<<(LBL * FF + 255) / 256, 256, 0, stream>>>(K, b, W, w2, cvec);
        crf_kernel<<<nw / WPB, 256, 0, stream>>>(X, T, w2, cvec, out);
    }
}